// Round 3
// baseline (1423.424 us; speedup 1.0000x reference)
//
#include <hip/hip_runtime.h>
#include <math.h>

#define B_ 16
#define H_ 96
#define W_ 96
#define C_ 128
#define HW_ (H_*W_)            // 9216
#define NTOK (B_*HW_)          // 147456
#define NOUT 260

// fused conv tile geometry
#define TH 16
#define TW 32
#define B0H 28
#define B0W 44
#define B1H 26
#define B1W 42
#define B2H 22
#define B2W 38

typedef unsigned short ushort_t;
typedef unsigned int uint_t;

__device__ __forceinline__ float gelu_f(float t) {
    return 0.5f * t * (1.0f + erff(t * 0.7071067811865475f));
}
__device__ __forceinline__ float b2f(ushort_t u) {
    union { unsigned int i; float f; } t; t.i = (unsigned int)u << 16; return t.f;
}
__device__ __forceinline__ ushort_t f2b(float f) {
    union { float f; unsigned int i; } t; t.f = f;
    unsigned int lsb = (t.i >> 16) & 1u;
    t.i += 0x7fffu + lsb;            // round-to-nearest-even
    return (ushort_t)(t.i >> 16);
}
__device__ __forceinline__ void unp2(uint_t u, float& a, float& b) {
    union { unsigned int i; float f; } x, y;
    x.i = u << 16; y.i = u & 0xffff0000u;
    a = x.f; b = y.f;
}
__device__ __forceinline__ void unp8(const uint4 v, float* f) {
    unp2(v.x, f[0], f[1]); unp2(v.y, f[2], f[3]);
    unp2(v.z, f[4], f[5]); unp2(v.w, f[6], f[7]);
}
__device__ __forceinline__ uint_t pk2(float a, float b) {
    return (uint_t)f2b(a) | ((uint_t)f2b(b) << 16);
}
__device__ __forceinline__ uint4 pk8(const float* f) {
    uint4 v;
    v.x = pk2(f[0], f[1]); v.y = pk2(f[2], f[3]);
    v.z = pk2(f[4], f[5]); v.w = pk2(f[6], f[7]);
    return v;
}

// ---------------------------------------------------------------------------
// K1: ctx = (x @ Wf)[:, 128:256] + bf ; gates = (x @ Wf)[:, 256:260] + bf
// Also zeroes csum (first 8 blocks) for the fused conv kernel's atomics.
// ---------------------------------------------------------------------------
__global__ __launch_bounds__(256) void gemm_ctx_gates(
    const float* __restrict__ x, const float* __restrict__ Wf,
    const float* __restrict__ bf,
    ushort_t* __restrict__ ctx, float* __restrict__ gates,
    float* __restrict__ csum)
{
    __shared__ float As[128][64];
    __shared__ float Bs[128][64];
    const int tid  = threadIdx.x;
    const int tok0 = blockIdx.x * 64;
    const int t    = tid & 63;
    const int k4   = (tid >> 6) << 2;

    if (blockIdx.x < 8) {           // zero the mean accumulator (2048 floats)
        csum[blockIdx.x * 256 + tid] = 0.0f;
    }

    {   // x tile transposed into As[k][t]
        const float* xp = x + (size_t)(tok0 + t) * C_;
        #pragma unroll
        for (int kk = k4; kk < C_; kk += 16) {
            float4 v = *(const float4*)(xp + kk);
            As[kk+0][t] = v.x; As[kk+1][t] = v.y;
            As[kk+2][t] = v.z; As[kk+3][t] = v.w;
        }
    }

    const int tx = tid & 15;
    const int ty = tid >> 4;
    const int n4 = tx << 2;

    for (int chunk = 0; chunk < 2; ++chunk) {
        const int n0 = C_ + (chunk << 6);
        __syncthreads();
        #pragma unroll
        for (int kk = ty; kk < C_; kk += 16)
            *(float4*)&Bs[kk][n4] = *(const float4*)(Wf + (size_t)kk * NOUT + n0 + n4);
        __syncthreads();

        float acc[16] = {};
        #pragma unroll 4
        for (int k = 0; k < C_; ++k) {
            const float4 a = *(const float4*)&As[k][ty << 2];
            const float4 b = *(const float4*)&Bs[k][n4];
            const float av[4] = {a.x, a.y, a.z, a.w};
            const float bv[4] = {b.x, b.y, b.z, b.w};
            #pragma unroll
            for (int i = 0; i < 4; ++i)
                #pragma unroll
                for (int j = 0; j < 4; ++j)
                    acc[i*4+j] += av[i] * bv[j];
        }

        const int col = (n0 - C_) + n4;
        const float4 bias = *(const float4*)(bf + n0 + n4);
        #pragma unroll
        for (int i = 0; i < 4; ++i) {
            const int token = tok0 + (ty << 2) + i;
            ushort4 r;
            r.x = f2b(acc[i*4+0] + bias.x);
            r.y = f2b(acc[i*4+1] + bias.y);
            r.z = f2b(acc[i*4+2] + bias.z);
            r.w = f2b(acc[i*4+3] + bias.w);
            *(ushort4*)(ctx + (size_t)token * C_ + col) = r;
        }
    }

    {   // gates: cols 256..259
        const int tt = tid & 63;
        const int g  = tid >> 6;
        float s = 0.f;
        #pragma unroll 8
        for (int k = 0; k < C_; ++k)
            s += As[k][tt] * Wf[(size_t)k * NOUT + 2*C_ + g];
        gates[(size_t)(tok0 + tt) * 4 + g] = s + bf[2*C_ + g];
    }
}

// ---------------------------------------------------------------------------
// K2 (fused): conv3->gelu->conv5->gelu->conv7->gelu cascade, all in LDS.
// Per block: 16x32 output pixels x 8 channels. Writes ctx_all (gated sum of
// the three levels) and atomically accumulates per-(b,c) sums of final ctx.
// ---------------------------------------------------------------------------
__global__ __launch_bounds__(256) void focal_conv_fused(
    const ushort_t* __restrict__ ctx_in,
    const float* __restrict__ k0w, const float* __restrict__ k1w,
    const float* __restrict__ k2w,
    const float* __restrict__ gates,
    ushort_t* __restrict__ ctx_all,
    float* __restrict__ csum)
{
    __shared__ uint4 buf0[B0H*B0W];            // 19712 B
    __shared__ uint4 buf1[B1H*B1W];            // 17472 B
    __shared__ uint4 buf2[B2H*B2W];            // 13376 B
    __shared__ float wts[(9+25+49)*8];         //  2656 B  (53216 total)

    const int tid = threadIdx.x;
    const int wt  = blockIdx.x;                // 0..2
    const int ht  = blockIdx.y;                // 0..5
    const int bz  = blockIdx.z;                // 0..255
    const int bb  = bz >> 4;
    const int c0  = (bz & 15) << 3;
    const int h0  = ht * TH, w0 = wt * TW;

    // weights -> LDS (fp32, 83 taps x 8 ch = 664 floats)
    if (tid < 166) {
        const int f = tid << 2;
        const float* src; int r;
        if (f < 72)       { r = f;       src = k0w; }
        else if (f < 272) { r = f - 72;  src = k1w; }
        else              { r = f - 272; src = k2w; }
        const int tap = r >> 3, off = r & 7;
        *(float4*)&wts[f] = *(const float4*)(src + tap * C_ + c0 + off);
    }

    // stage 0: global -> buf0 (zero-pad outside image)
    const size_t baseB = (size_t)bb * HW_ * C_;
    for (int i = tid; i < B0H*B0W; i += 256) {
        const int r = i / B0W, q = i - r * B0W;
        const int hh = h0 - 6 + r, ww = w0 - 6 + q;
        uint4 v = make_uint4(0u, 0u, 0u, 0u);
        if ((unsigned)hh < (unsigned)H_ && (unsigned)ww < (unsigned)W_)
            v = *(const uint4*)(ctx_in + baseB + (size_t)(hh * W_ + ww) * C_ + c0);
        buf0[i] = v;
    }
    __syncthreads();

    // stage 1: buf1 = gelu(conv3(buf0))
    for (int e = tid; e < B1H*B1W; e += 256) {
        const int i = e / B1W, j = e - i * B1W;
        float acc[8] = {};
        #pragma unroll
        for (int a = 0; a < 3; ++a)
            #pragma unroll
            for (int b = 0; b < 3; ++b) {
                float d[8]; unp8(buf0[(i+a)*B0W + (j+b)], d);
                const float* wp = &wts[(a*3 + b) * 8];
                #pragma unroll
                for (int c = 0; c < 8; ++c) acc[c] += d[c] * wp[c];
            }
        float g[8];
        #pragma unroll
        for (int c = 0; c < 8; ++c) g[c] = gelu_f(acc[c]);
        buf1[e] = pk8(g);
    }
    __syncthreads();

    // stage 2: buf2 = gelu(conv5(buf1))
    for (int e = tid; e < B2H*B2W; e += 256) {
        const int i = e / B2W, j = e - i * B2W;
        float acc[8] = {};
        #pragma unroll
        for (int a = 0; a < 5; ++a)
            #pragma unroll
            for (int b = 0; b < 5; ++b) {
                float d[8]; unp8(buf1[(i+a)*B1W + (j+b)], d);
                const float* wp = &wts[72 + (a*5 + b) * 8];
                #pragma unroll
                for (int c = 0; c < 8; ++c) acc[c] += d[c] * wp[c];
            }
        float g[8];
        #pragma unroll
        for (int c = 0; c < 8; ++c) g[c] = gelu_f(acc[c]);
        buf2[e] = pk8(g);
    }
    __syncthreads();

    // stage 3: ctx3 = gelu(conv7(buf2)); ctx_all = ctx1*g0 + ctx2*g1 + ctx3*g2
    float lsum[8] = {};
    for (int e = tid; e < TH*TW; e += 256) {   // 2 iterations
        const int th = e >> 5, tw = e & 31;
        float acc[8] = {};
        #pragma unroll
        for (int a = 0; a < 7; ++a)
            #pragma unroll
            for (int b = 0; b < 7; ++b) {
                float d[8]; unp8(buf2[(th+a)*B2W + (tw+b)], d);
                const float* wp = &wts[272 + (a*7 + b) * 8];
                #pragma unroll
                for (int c = 0; c < 8; ++c) acc[c] += d[c] * wp[c];
            }
        float ctx3[8];
        #pragma unroll
        for (int c = 0; c < 8; ++c) { ctx3[c] = gelu_f(acc[c]); lsum[c] += ctx3[c]; }

        float d1[8]; unp8(buf1[(5+th)*B1W + (5+tw)], d1);
        float d2[8]; unp8(buf2[(th+3)*B2W + (tw+3)], d2);

        const size_t pix = (size_t)bb * HW_ + (size_t)(h0 + th) * W_ + (w0 + tw);
        const float4 gt = *(const float4*)(gates + pix * 4);
        float o[8];
        #pragma unroll
        for (int c = 0; c < 8; ++c)
            o[c] = d1[c] * gt.x + d2[c] * gt.y + ctx3[c] * gt.z;
        *(uint4*)(ctx_all + pix * C_ + c0) = pk8(o);
    }

    // per-block channel sums of final ctx -> atomic accumulate
    __syncthreads();
    float* red = (float*)buf0;   // 8 KB needed, buf0 dead
    #pragma unroll
    for (int c = 0; c < 8; ++c) red[c*256 + tid] = lsum[c];
    __syncthreads();
    for (int off = 128; off > 0; off >>= 1) {
        if (tid < off) {
            #pragma unroll
            for (int c = 0; c < 8; ++c)
                red[c*256 + tid] += red[c*256 + tid + off];
        }
        __syncthreads();
    }
    if (tid < 8) atomicAdd(&csum[bb * C_ + c0 + tid], red[tid * 256]);
}

// ---------------------------------------------------------------------------
// K3: cglob = gelu(csum / HW)   (2048 elements)
// ---------------------------------------------------------------------------
__global__ __launch_bounds__(256) void mean_fin(
    const float* __restrict__ csum, float* __restrict__ cglob)
{
    const int i = blockIdx.x * 256 + threadIdx.x;
    if (i < B_ * C_) cglob[i] = gelu_f(csum[i] * (1.0f / (float)HW_));
}

// ---------------------------------------------------------------------------
// K4: mod = (ctx_all + cglob*g3) @ Wh + bh ; q = x @ Wf[:, :C] + bf[:C] ;
//     x_out = q * mod ; LayerNorm -> xln (bf16)
// ---------------------------------------------------------------------------
__global__ __launch_bounds__(256) void modq_ln(
    const ushort_t* __restrict__ ctx_all, const float* __restrict__ cglob,
    const float* __restrict__ gates, const float* __restrict__ x,
    const float* __restrict__ Wf, const float* __restrict__ bf,
    const float* __restrict__ Wh, const float* __restrict__ bh,
    const float* __restrict__ gamma, const float* __restrict__ beta,
    ushort_t* __restrict__ xln)
{
    __shared__ float smem[12288 + 128];
    float (*As)[64]  = (float(*)[64])smem;
    float (*Bs)[128] = (float(*)[128])(smem + 4096);
    float (*xs)[132] = (float(*)[132])smem;
    float* mu_s = smem + 12288;
    float* rs_s = smem + 12288 + 64;

    const int tid  = threadIdx.x;
    const int tok0 = blockIdx.x * 64;
    const int bidx = tok0 / HW_;
    const int t    = tid & 63;
    const int k4   = (tid >> 6) << 2;
    const int tx   = tid & 15, ty = tid >> 4;
    const float g3 = gates[(size_t)(tok0 + t) * 4 + 3];

    float acc_m[32] = {};
    float acc_q[32] = {};

    for (int kc = 0; kc < C_; kc += 64) {
        __syncthreads();
        {
            const ushort_t* ap = ctx_all + (size_t)(tok0 + t) * C_ + kc;
            const float* gp = cglob + bidx * C_ + kc;
            #pragma unroll
            for (int kk = k4; kk < 64; kk += 16) {
                const ushort4 u = *(const ushort4*)(ap + kk);
                const float4 cg = *(const float4*)(gp + kk);
                As[kk+0][t] = b2f(u.x) + cg.x * g3;
                As[kk+1][t] = b2f(u.y) + cg.y * g3;
                As[kk+2][t] = b2f(u.z) + cg.z * g3;
                As[kk+3][t] = b2f(u.w) + cg.w * g3;
            }
        }
        {
            const int n4b = (tid & 31) << 2;
            const int kr  = tid >> 5;
            #pragma unroll
            for (int kk = kr; kk < 64; kk += 8)
                *(float4*)&Bs[kk][n4b] = *(const float4*)(Wh + (size_t)(kc + kk) * C_ + n4b);
        }
        __syncthreads();
        #pragma unroll 4
        for (int k = 0; k < 64; ++k) {
            const float4 a  = *(const float4*)&As[k][ty << 2];
            const float4 b0 = *(const float4*)&Bs[k][tx << 2];
            const float4 b1 = *(const float4*)&Bs[k][64 + (tx << 2)];
            const float av[4] = {a.x, a.y, a.z, a.w};
            const float bv[8] = {b0.x, b0.y, b0.z, b0.w, b1.x, b1.y, b1.z, b1.w};
            #pragma unroll
            for (int i = 0; i < 4; ++i)
                #pragma unroll
                for (int j = 0; j < 8; ++j)
                    acc_m[i*8+j] += av[i] * bv[j];
        }
    }

    for (int kc = 0; kc < C_; kc += 64) {
        __syncthreads();
        {
            const float* ap = x + (size_t)(tok0 + t) * C_ + kc;
            #pragma unroll
            for (int kk = k4; kk < 64; kk += 16) {
                const float4 v = *(const float4*)(ap + kk);
                As[kk+0][t] = v.x; As[kk+1][t] = v.y;
                As[kk+2][t] = v.z; As[kk+3][t] = v.w;
            }
        }
        {
            const int n4b = (tid & 31) << 2;
            const int kr  = tid >> 5;
            #pragma unroll
            for (int kk = kr; kk < 64; kk += 8)
                *(float4*)&Bs[kk][n4b] = *(const float4*)(Wf + (size_t)(kc + kk) * NOUT + n4b);
        }
        __syncthreads();
        #pragma unroll 4
        for (int k = 0; k < 64; ++k) {
            const float4 a  = *(const float4*)&As[k][ty << 2];
            const float4 b0 = *(const float4*)&Bs[k][tx << 2];
            const float4 b1 = *(const float4*)&Bs[k][64 + (tx << 2)];
            const float av[4] = {a.x, a.y, a.z, a.w};
            const float bv[8] = {b0.x, b0.y, b0.z, b0.w, b1.x, b1.y, b1.z, b1.w};
            #pragma unroll
            for (int i = 0; i < 4; ++i)
                #pragma unroll
                for (int j = 0; j < 8; ++j)
                    acc_q[i*8+j] += av[i] * bv[j];
        }
    }
    __syncthreads();

    {
        const int n1 = tx << 2, n2 = 64 + (tx << 2);
        const float4 bh1 = *(const float4*)(bh + n1);
        const float4 bh2 = *(const float4*)(bh + n2);
        const float4 bf1 = *(const float4*)(bf + n1);
        const float4 bf2 = *(const float4*)(bf + n2);
        #pragma unroll
        for (int i = 0; i < 4; ++i) {
            const int m = (ty << 2) + i;
            xs[m][n1+0] = (acc_q[i*8+0] + bf1.x) * (acc_m[i*8+0] + bh1.x);
            xs[m][n1+1] = (acc_q[i*8+1] + bf1.y) * (acc_m[i*8+1] + bh1.y);
            xs[m][n1+2] = (acc_q[i*8+2] + bf1.z) * (acc_m[i*8+2] + bh1.z);
            xs[m][n1+3] = (acc_q[i*8+3] + bf1.w) * (acc_m[i*8+3] + bh1.w);
            xs[m][n2+0] = (acc_q[i*8+4] + bf2.x) * (acc_m[i*8+4] + bh2.x);
            xs[m][n2+1] = (acc_q[i*8+5] + bf2.y) * (acc_m[i*8+5] + bh2.y);
            xs[m][n2+2] = (acc_q[i*8+6] + bf2.z) * (acc_m[i*8+6] + bh2.z);
            xs[m][n2+3] = (acc_q[i*8+7] + bf2.w) * (acc_m[i*8+7] + bh2.w);
        }
    }
    __syncthreads();

    if (tid < 64) {
        float s = 0.f, s2 = 0.f;
        #pragma unroll
        for (int c = 0; c < C_; c += 4) {
            const float4 v = *(const float4*)&xs[tid][c];
            s  += v.x + v.y + v.z + v.w;
            s2 += v.x*v.x + v.y*v.y + v.z*v.z + v.w*v.w;
        }
        const float mu  = s * (1.0f / 128.0f);
        const float var = s2 * (1.0f / 128.0f) - mu * mu;
        mu_s[tid] = mu;
        rs_s[tid] = rsqrtf(var + 0.001f);
    }
    __syncthreads();

    {
        const int tt = tid >> 2;
        const int c0 = (tid & 3) << 5;
        const float mu = mu_s[tt], rs = rs_s[tt];
        ushort_t* op = xln + (size_t)(tok0 + tt) * C_;
        #pragma unroll
        for (int j = 0; j < 8; ++j) {
            const int c = c0 + (j << 2);
            const float4 v  = *(const float4*)&xs[tt][c];
            const float4 gm = *(const float4*)(gamma + c);
            const float4 bt = *(const float4*)(beta + c);
            ushort4 o;
            o.x = f2b((v.x - mu) * rs * gm.x + bt.x);
            o.y = f2b((v.y - mu) * rs * gm.y + bt.y);
            o.z = f2b((v.z - mu) * rs * gm.z + bt.z);
            o.w = f2b((v.w - mu) * rs * gm.w + bt.w);
            *(ushort4*)(op + c) = o;
        }
    }
}

// ---------------------------------------------------------------------------
// K5: out = xln @ Wp + bp   (xln bf16, out fp32)
// ---------------------------------------------------------------------------
__global__ __launch_bounds__(256) void gemm_out(
    const ushort_t* __restrict__ xln, const float* __restrict__ Wp,
    const float* __restrict__ bp, float* __restrict__ out)
{
    __shared__ float smem[12288];
    float (*As)[64]  = (float(*)[64])smem;
    float (*Bs)[128] = (float(*)[128])(smem + 4096);

    const int tid  = threadIdx.x;
    const int tok0 = blockIdx.x * 64;
    const int t    = tid & 63;
    const int k4   = (tid >> 6) << 2;
    const int tx   = tid & 15, ty = tid >> 4;

    float acc[32] = {};
    for (int kc = 0; kc < C_; kc += 64) {
        __syncthreads();
        {
            const ushort_t* ap = xln + (size_t)(tok0 + t) * C_ + kc;
            #pragma unroll
            for (int kk = k4; kk < 64; kk += 16) {
                const ushort4 u = *(const ushort4*)(ap + kk);
                As[kk+0][t] = b2f(u.x); As[kk+1][t] = b2f(u.y);
                As[kk+2][t] = b2f(u.z); As[kk+3][t] = b2f(u.w);
            }
        }
        {
            const int n4b = (tid & 31) << 2;
            const int kr  = tid >> 5;
            #pragma unroll
            for (int kk = kr; kk < 64; kk += 8)
                *(float4*)&Bs[kk][n4b] = *(const float4*)(Wp + (size_t)(kc + kk) * C_ + n4b);
        }
        __syncthreads();
        #pragma unroll 4
        for (int k = 0; k < 64; ++k) {
            const float4 a  = *(const float4*)&As[k][ty << 2];
            const float4 b0 = *(const float4*)&Bs[k][tx << 2];
            const float4 b1 = *(const float4*)&Bs[k][64 + (tx << 2)];
            const float av[4] = {a.x, a.y, a.z, a.w};
            const float bv[8] = {b0.x, b0.y, b0.z, b0.w, b1.x, b1.y, b1.z, b1.w};
            #pragma unroll
            for (int i = 0; i < 4; ++i)
                #pragma unroll
                for (int j = 0; j < 8; ++j)
                    acc[i*8+j] += av[i] * bv[j];
        }
    }

    const int n1 = tx << 2, n2 = 64 + (tx << 2);
    const float4 b1 = *(const float4*)(bp + n1);
    const float4 b2 = *(const float4*)(bp + n2);
    #pragma unroll
    for (int i = 0; i < 4; ++i) {
        const int token = tok0 + (ty << 2) + i;
        float4 r1, r2;
        r1.x = acc[i*8+0] + b1.x; r1.y = acc[i*8+1] + b1.y;
        r1.z = acc[i*8+2] + b1.z; r1.w = acc[i*8+3] + b1.w;
        r2.x = acc[i*8+4] + b2.x; r2.y = acc[i*8+5] + b2.y;
        r2.z = acc[i*8+6] + b2.z; r2.w = acc[i*8+7] + b2.w;
        *(float4*)(out + (size_t)token * C_ + n1) = r1;
        *(float4*)(out + (size_t)token * C_ + n2) = r2;
    }
}

// ---------------------------------------------------------------------------
extern "C" void kernel_launch(void* const* d_in, const int* in_sizes, int n_in,
                              void* d_out, int out_size, void* d_ws, size_t ws_size,
                              hipStream_t stream) {
    const float* x     = (const float*)d_in[0];
    const float* Wf    = (const float*)d_in[1];
    const float* bf    = (const float*)d_in[2];
    const float* Wh    = (const float*)d_in[3];
    const float* bh    = (const float*)d_in[4];
    const float* gamma = (const float*)d_in[5];
    const float* beta  = (const float*)d_in[6];
    const float* Wp    = (const float*)d_in[7];
    const float* bp    = (const float*)d_in[8];
    const float* k0    = (const float*)d_in[9];
    const float* k1    = (const float*)d_in[10];
    const float* k2    = (const float*)d_in[11];
    float* out = (float*)d_out;

    const size_t NC = (size_t)NTOK * C_;
    ushort_t* P0  = (ushort_t*)d_ws;          // ctx (then reused as xln)
    ushort_t* ACC = P0 + NC;                  // ctx_all
    float* gates  = (float*)(ACC + NC);
    float* csum   = gates + (size_t)NTOK * 4;
    float* cglob  = csum + (size_t)B_ * C_;
    // total: 2*NC*2 + NTOK*16 + 2*B*C*4 B  ~= 78 MB

    gemm_ctx_gates<<<NTOK / 64, 256, 0, stream>>>(x, Wf, bf, P0, gates, csum);
    focal_conv_fused<<<dim3(W_/TW, H_/TH, B_ * (C_/8)), 256, 0, stream>>>(
        P0, k0, k1, k2, gates, ACC, csum);
    mean_fin<<<(B_ * C_ + 255) / 256, 256, 0, stream>>>(csum, cglob);
    modq_ln<<<NTOK / 64, 256, 0, stream>>>(ACC, cglob, gates, x, Wf, bf, Wh, bh, gamma, beta, P0);
    gemm_out<<<NTOK / 64, 256, 0, stream>>>(P0, Wp, bp, out);
}

// Round 4
// 603.047 us; speedup vs baseline: 2.3604x; 2.3604x over previous
//
#include <hip/hip_runtime.h>
#include <math.h>

#define B_ 16
#define H_ 96
#define W_ 96
#define C_ 128
#define HW_ (H_*W_)            // 9216
#define NTOK (B_*HW_)          // 147456
#define NOUT 260

// fused conv tile geometry
#define TH 16
#define TW 32
#define B0H 28
#define B0W 44
#define B1H 26
#define B1W 42
#define B2H 22
#define B2W 38

typedef unsigned short ushort_t;
typedef unsigned int uint_t;

__device__ __forceinline__ float gelu_f(float t) {
    return 0.5f * t * (1.0f + erff(t * 0.7071067811865475f));
}
__device__ __forceinline__ float b2f(ushort_t u) {
    union { unsigned int i; float f; } t; t.i = (unsigned int)u << 16; return t.f;
}
__device__ __forceinline__ ushort_t f2b(float f) {
    union { float f; unsigned int i; } t; t.f = f;
    unsigned int lsb = (t.i >> 16) & 1u;
    t.i += 0x7fffu + lsb;            // round-to-nearest-even
    return (ushort_t)(t.i >> 16);
}
__device__ __forceinline__ void unp2(uint_t u, float& a, float& b) {
    union { unsigned int i; float f; } x, y;
    x.i = u << 16; y.i = u & 0xffff0000u;
    a = x.f; b = y.f;
}
__device__ __forceinline__ void unp8(const uint4 v, float* f) {
    unp2(v.x, f[0], f[1]); unp2(v.y, f[2], f[3]);
    unp2(v.z, f[4], f[5]); unp2(v.w, f[6], f[7]);
}
__device__ __forceinline__ uint_t pk2(float a, float b) {
    return (uint_t)f2b(a) | ((uint_t)f2b(b) << 16);
}
__device__ __forceinline__ uint4 pk8(const float* f) {
    uint4 v;
    v.x = pk2(f[0], f[1]); v.y = pk2(f[2], f[3]);
    v.z = pk2(f[4], f[5]); v.w = pk2(f[6], f[7]);
    return v;
}

// ---------------------------------------------------------------------------
// K1: ctx = (x @ Wf)[:, 128:256] + bf ; gates = (x @ Wf)[:, 256:260] + bf
// ctx stored bf16 in TRANSPOSED layout [C/8][NTOK][8] for the conv kernel.
// Also zeroes csum (first 8 blocks).
// ---------------------------------------------------------------------------
__global__ __launch_bounds__(256) void gemm_ctx_gates(
    const float* __restrict__ x, const float* __restrict__ Wf,
    const float* __restrict__ bf,
    ushort_t* __restrict__ ctx, float* __restrict__ gates,
    float* __restrict__ csum)
{
    __shared__ float As[128][64];
    __shared__ float Bs[128][64];
    const int tid  = threadIdx.x;
    const int tok0 = blockIdx.x * 64;
    const int t    = tid & 63;
    const int k4   = (tid >> 6) << 2;

    if (blockIdx.x < 8) csum[blockIdx.x * 256 + tid] = 0.0f;

    {   // x tile transposed into As[k][t]
        const float* xp = x + (size_t)(tok0 + t) * C_;
        #pragma unroll
        for (int kk = k4; kk < C_; kk += 16) {
            float4 v = *(const float4*)(xp + kk);
            As[kk+0][t] = v.x; As[kk+1][t] = v.y;
            As[kk+2][t] = v.z; As[kk+3][t] = v.w;
        }
    }

    const int tx = tid & 15;
    const int ty = tid >> 4;
    const int n4 = tx << 2;

    for (int chunk = 0; chunk < 2; ++chunk) {
        const int n0 = C_ + (chunk << 6);
        __syncthreads();
        #pragma unroll
        for (int kk = ty; kk < C_; kk += 16)
            *(float4*)&Bs[kk][n4] = *(const float4*)(Wf + (size_t)kk * NOUT + n0 + n4);
        __syncthreads();

        float acc[16] = {};
        #pragma unroll 4
        for (int k = 0; k < C_; ++k) {
            const float4 a = *(const float4*)&As[k][ty << 2];
            const float4 b = *(const float4*)&Bs[k][n4];
            const float av[4] = {a.x, a.y, a.z, a.w};
            const float bv[4] = {b.x, b.y, b.z, b.w};
            #pragma unroll
            for (int i = 0; i < 4; ++i)
                #pragma unroll
                for (int j = 0; j < 4; ++j)
                    acc[i*4+j] += av[i] * bv[j];
        }

        const int col = (n0 - C_) + n4;       // 0..255 within ctx
        const float4 bias = *(const float4*)(bf + n0 + n4);
        #pragma unroll
        for (int i = 0; i < 4; ++i) {
            const int token = tok0 + (ty << 2) + i;
            ushort4 r;
            r.x = f2b(acc[i*4+0] + bias.x);
            r.y = f2b(acc[i*4+1] + bias.y);
            r.z = f2b(acc[i*4+2] + bias.z);
            r.w = f2b(acc[i*4+3] + bias.w);
            // transposed store: [col>>3][token][col&7]
            *(ushort4*)(ctx + (((size_t)(col >> 3) * NTOK + token) << 3) + (col & 7)) = r;
        }
    }

    {   // gates: cols 256..259
        const int tt = tid & 63;
        const int g  = tid >> 6;
        float s = 0.f;
        #pragma unroll 8
        for (int k = 0; k < C_; ++k)
            s += As[k][tt] * Wf[(size_t)k * NOUT + 2*C_ + g];
        gates[(size_t)(tok0 + tt) * 4 + g] = s + bf[2*C_ + g];
    }
}

// ---------------------------------------------------------------------------
// K2 (fused): conv3->gelu->conv5->gelu->conv7->gelu cascade in LDS.
// Tap-outer loops (weights loaded once per tap, no mass hoisting), LDS alias
// buf2 -> buf0, ctx input in transposed layout.
// ---------------------------------------------------------------------------
__global__ __launch_bounds__(256, 4) void focal_conv_fused(
    const ushort_t* __restrict__ ctx_in,
    const float* __restrict__ k0w, const float* __restrict__ k1w,
    const float* __restrict__ k2w,
    const float* __restrict__ gates,
    ushort_t* __restrict__ ctx_all,
    float* __restrict__ csum)
{
    __shared__ uint4 bufA[B0H*B0W];            // 19712 B (stage0 in; stage2 out 22x38)
    __shared__ uint4 buf1[B1H*B1W];            // 17472 B
    __shared__ float wts[(9+25+49)*8];         //  2656 B   (39840 total)

    const int tid  = threadIdx.x;
    const int cg   = blockIdx.x;               // 0..15 channel group
    const int tile = blockIdx.y;               // 0..17
    const int bb   = blockIdx.z;               // 0..15
    const int wt   = tile % 3, ht = tile / 3;
    const int c0   = cg << 3;
    const int h0   = ht * TH, w0 = wt * TW;

    // weights -> LDS (83 taps x 8 ch)
    if (tid < 166) {
        const int f = tid << 2;
        const float* src; int r;
        if (f < 72)       { r = f;       src = k0w; }
        else if (f < 272) { r = f - 72;  src = k1w; }
        else              { r = f - 272; src = k2w; }
        const int tap = r >> 3, off = r & 7;
        *(float4*)&wts[f] = *(const float4*)(src + tap * C_ + c0 + off);
    }

    // stage 0: global -> bufA (contiguous reads from transposed ctx)
    const ushort_t* cin = ctx_in + (((size_t)cg * NTOK + (size_t)bb * HW_) << 3);
    for (int i = tid; i < B0H*B0W; i += 256) {
        const int r = i / B0W, q = i - r * B0W;
        const int hh = h0 - 6 + r, ww = w0 - 6 + q;
        uint4 v = make_uint4(0u, 0u, 0u, 0u);
        if ((unsigned)hh < (unsigned)H_ && (unsigned)ww < (unsigned)W_)
            v = *(const uint4*)(cin + ((size_t)(hh * W_ + ww) << 3));
        bufA[i] = v;
    }
    __syncthreads();

    // ---- stage 1: buf1 = gelu(conv3(bufA))  [26x42] ----
    {
        int iv[5], ecp[5], boff[5];
        #pragma unroll
        for (int p = 0; p < 5; ++p) {
            const int e = tid + (p << 8);
            iv[p] = (e < B1H*B1W);
            const int ec = iv[p] ? e : 0;
            ecp[p] = ec;
            boff[p] = (ec / B1W) * B0W + (ec % B1W);
        }
        float acc[5][8] = {};
        #pragma unroll 1
        for (int a = 0; a < 3; ++a) {
            #pragma unroll
            for (int b = 0; b < 3; ++b) {
                float wv[8];
                *(float4*)&wv[0] = *(const float4*)&wts[(a*3+b)*8];
                *(float4*)&wv[4] = *(const float4*)&wts[(a*3+b)*8 + 4];
                const int off = a * B0W + b;
                #pragma unroll
                for (int p = 0; p < 5; ++p) {
                    float d[8]; unp8(bufA[boff[p] + off], d);
                    #pragma unroll
                    for (int c = 0; c < 8; ++c) acc[p][c] += d[c] * wv[c];
                }
            }
        }
        __syncthreads();   // all bufA reads done before stage2 overwrites it
        #pragma unroll
        for (int p = 0; p < 5; ++p) if (iv[p]) {
            float g[8];
            #pragma unroll
            for (int c = 0; c < 8; ++c) g[c] = gelu_f(acc[p][c]);
            buf1[ecp[p]] = pk8(g);
        }
    }
    __syncthreads();

    // ---- stage 2: bufA = gelu(conv5(buf1))  [22x38] ----
    {
        int iv[4], ecp[4], boff[4];
        #pragma unroll
        for (int p = 0; p < 4; ++p) {
            const int e = tid + (p << 8);
            iv[p] = (e < B2H*B2W);
            const int ec = iv[p] ? e : 0;
            ecp[p] = ec;
            boff[p] = (ec / B2W) * B1W + (ec % B2W);
        }
        float acc[4][8] = {};
        #pragma unroll 1
        for (int a = 0; a < 5; ++a) {
            #pragma unroll
            for (int b = 0; b < 5; ++b) {
                float wv[8];
                *(float4*)&wv[0] = *(const float4*)&wts[72 + (a*5+b)*8];
                *(float4*)&wv[4] = *(const float4*)&wts[72 + (a*5+b)*8 + 4];
                const int off = a * B1W + b;
                #pragma unroll
                for (int p = 0; p < 4; ++p) {
                    float d[8]; unp8(buf1[boff[p] + off], d);
                    #pragma unroll
                    for (int c = 0; c < 8; ++c) acc[p][c] += d[c] * wv[c];
                }
            }
        }
        __syncthreads();   // bufA stage-0 data fully dead (stage1 done) — safe to overwrite
        #pragma unroll
        for (int p = 0; p < 4; ++p) if (iv[p]) {
            float g[8];
            #pragma unroll
            for (int c = 0; c < 8; ++c) g[c] = gelu_f(acc[p][c]);
            bufA[ecp[p]] = pk8(g);
        }
    }
    __syncthreads();

    // ---- stage 3: ctx3 = gelu(conv7(bufA)); combine 3 gated levels ----
    float lsum[8] = {};
    {
        const int th0 = tid >> 5, tw0 = tid & 31;   // p adds 8 to th
        float acc[2][8] = {};
        #pragma unroll 1
        for (int a = 0; a < 7; ++a) {
            #pragma unroll
            for (int b = 0; b < 7; ++b) {
                float wv[8];
                *(float4*)&wv[0] = *(const float4*)&wts[272 + (a*7+b)*8];
                *(float4*)&wv[4] = *(const float4*)&wts[272 + (a*7+b)*8 + 4];
                #pragma unroll
                for (int p = 0; p < 2; ++p) {
                    const int th = th0 + (p << 3);
                    float d[8]; unp8(bufA[(th + a)*B2W + (tw0 + b)], d);
                    #pragma unroll
                    for (int c = 0; c < 8; ++c) acc[p][c] += d[c] * wv[c];
                }
            }
        }
        #pragma unroll
        for (int p = 0; p < 2; ++p) {
            const int th = th0 + (p << 3);
            float ctx3[8];
            #pragma unroll
            for (int c = 0; c < 8; ++c) { ctx3[c] = gelu_f(acc[p][c]); lsum[c] += ctx3[c]; }
            float d1[8]; unp8(buf1[(5+th)*B1W + (5+tw0)], d1);
            float d2[8]; unp8(bufA[(th+3)*B2W + (tw0+3)], d2);
            const size_t pix = (size_t)bb * HW_ + (size_t)(h0 + th) * W_ + (w0 + tw0);
            const float4 gt = *(const float4*)(gates + pix * 4);
            float o[8];
            #pragma unroll
            for (int c = 0; c < 8; ++c)
                o[c] = d1[c] * gt.x + d2[c] * gt.y + ctx3[c] * gt.z;
            *(uint4*)(ctx_all + pix * C_ + c0) = pk8(o);
        }
    }

    // per-block channel sums of final ctx -> atomic accumulate
    __syncthreads();
    float* red = (float*)bufA;
    #pragma unroll
    for (int c = 0; c < 8; ++c) red[c*256 + tid] = lsum[c];
    __syncthreads();
    for (int off = 128; off > 0; off >>= 1) {
        if (tid < off) {
            #pragma unroll
            for (int c = 0; c < 8; ++c)
                red[c*256 + tid] += red[c*256 + tid + off];
        }
        __syncthreads();
    }
    if (tid < 8) atomicAdd(&csum[bb * C_ + c0 + tid], red[tid * 256]);
}

// ---------------------------------------------------------------------------
// K3: cglob = gelu(csum / HW)
// ---------------------------------------------------------------------------
__global__ __launch_bounds__(256) void mean_fin(
    const float* __restrict__ csum, float* __restrict__ cglob)
{
    const int i = blockIdx.x * 256 + threadIdx.x;
    if (i < B_ * C_) cglob[i] = gelu_f(csum[i] * (1.0f / (float)HW_));
}

// ---------------------------------------------------------------------------
// K4: mod = (ctx_all + cglob*g3) @ Wh + bh ; q = x @ Wf[:, :C] + bf[:C] ;
//     x_out = q * mod ; LayerNorm -> xln (bf16, token-major)
// ---------------------------------------------------------------------------
__global__ __launch_bounds__(256) void modq_ln(
    const ushort_t* __restrict__ ctx_all, const float* __restrict__ cglob,
    const float* __restrict__ gates, const float* __restrict__ x,
    const float* __restrict__ Wf, const float* __restrict__ bf,
    const float* __restrict__ Wh, const float* __restrict__ bh,
    const float* __restrict__ gamma, const float* __restrict__ beta,
    ushort_t* __restrict__ xln)
{
    __shared__ float smem[12288 + 128];
    float (*As)[64]  = (float(*)[64])smem;
    float (*Bs)[128] = (float(*)[128])(smem + 4096);
    float (*xs)[132] = (float(*)[132])smem;
    float* mu_s = smem + 12288;
    float* rs_s = smem + 12288 + 64;

    const int tid  = threadIdx.x;
    const int tok0 = blockIdx.x * 64;
    const int bidx = tok0 / HW_;
    const int t    = tid & 63;
    const int k4   = (tid >> 6) << 2;
    const int tx   = tid & 15, ty = tid >> 4;
    const float g3 = gates[(size_t)(tok0 + t) * 4 + 3];

    float acc_m[32] = {};
    float acc_q[32] = {};

    for (int kc = 0; kc < C_; kc += 64) {
        __syncthreads();
        {
            const ushort_t* ap = ctx_all + (size_t)(tok0 + t) * C_ + kc;
            const float* gp = cglob + bidx * C_ + kc;
            #pragma unroll
            for (int kk = k4; kk < 64; kk += 16) {
                const ushort4 u = *(const ushort4*)(ap + kk);
                const float4 cg = *(const float4*)(gp + kk);
                As[kk+0][t] = b2f(u.x) + cg.x * g3;
                As[kk+1][t] = b2f(u.y) + cg.y * g3;
                As[kk+2][t] = b2f(u.z) + cg.z * g3;
                As[kk+3][t] = b2f(u.w) + cg.w * g3;
            }
        }
        {
            const int n4b = (tid & 31) << 2;
            const int kr  = tid >> 5;
            #pragma unroll
            for (int kk = kr; kk < 64; kk += 8)
                *(float4*)&Bs[kk][n4b] = *(const float4*)(Wh + (size_t)(kc + kk) * C_ + n4b);
        }
        __syncthreads();
        #pragma unroll 4
        for (int k = 0; k < 64; ++k) {
            const float4 a  = *(const float4*)&As[k][ty << 2];
            const float4 b0 = *(const float4*)&Bs[k][tx << 2];
            const float4 b1 = *(const float4*)&Bs[k][64 + (tx << 2)];
            const float av[4] = {a.x, a.y, a.z, a.w};
            const float bv[8] = {b0.x, b0.y, b0.z, b0.w, b1.x, b1.y, b1.z, b1.w};
            #pragma unroll
            for (int i = 0; i < 4; ++i)
                #pragma unroll
                for (int j = 0; j < 8; ++j)
                    acc_m[i*8+j] += av[i] * bv[j];
        }
    }

    for (int kc = 0; kc < C_; kc += 64) {
        __syncthreads();
        {
            const float* ap = x + (size_t)(tok0 + t) * C_ + kc;
            #pragma unroll
            for (int kk = k4; kk < 64; kk += 16) {
                const float4 v = *(const float4*)(ap + kk);
                As[kk+0][t] = v.x; As[kk+1][t] = v.y;
                As[kk+2][t] = v.z; As[kk+3][t] = v.w;
            }
        }
        {
            const int n4b = (tid & 31) << 2;
            const int kr  = tid >> 5;
            #pragma unroll
            for (int kk = kr; kk < 64; kk += 8)
                *(float4*)&Bs[kk][n4b] = *(const float4*)(Wf + (size_t)(kc + kk) * NOUT + n4b);
        }
        __syncthreads();
        #pragma unroll 4
        for (int k = 0; k < 64; ++k) {
            const float4 a  = *(const float4*)&As[k][ty << 2];
            const float4 b0 = *(const float4*)&Bs[k][tx << 2];
            const float4 b1 = *(const float4*)&Bs[k][64 + (tx << 2)];
            const float av[4] = {a.x, a.y, a.z, a.w};
            const float bv[8] = {b0.x, b0.y, b0.z, b0.w, b1.x, b1.y, b1.z, b1.w};
            #pragma unroll
            for (int i = 0; i < 4; ++i)
                #pragma unroll
                for (int j = 0; j < 8; ++j)
                    acc_q[i*8+j] += av[i] * bv[j];
        }
    }
    __syncthreads();

    {
        const int n1 = tx << 2, n2 = 64 + (tx << 2);
        const float4 bh1 = *(const float4*)(bh + n1);
        const float4 bh2 = *(const float4*)(bh + n2);
        const float4 bf1 = *(const float4*)(bf + n1);
        const float4 bf2 = *(const float4*)(bf + n2);
        #pragma unroll
        for (int i = 0; i < 4; ++i) {
            const int m = (ty << 2) + i;
            xs[m][n1+0] = (acc_q[i*8+0] + bf1.x) * (acc_m[i*8+0] + bh1.x);
            xs[m][n1+1] = (acc_q[i*8+1] + bf1.y) * (acc_m[i*8+1] + bh1.y);
            xs[m][n1+2] = (acc_q[i*8+2] + bf1.z) * (acc_m[i*8+2] + bh1.z);
            xs[m][n1+3] = (acc_q[i*8+3] + bf1.w) * (acc_m[i*8+3] + bh1.w);
            xs[m][n2+0] = (acc_q[i*8+4] + bf2.x) * (acc_m[i*8+4] + bh2.x);
            xs[m][n2+1] = (acc_q[i*8+5] + bf2.y) * (acc_m[i*8+5] + bh2.y);
            xs[m][n2+2] = (acc_q[i*8+6] + bf2.z) * (acc_m[i*8+6] + bh2.z);
            xs[m][n2+3] = (acc_q[i*8+7] + bf2.w) * (acc_m[i*8+7] + bh2.w);
        }
    }
    __syncthreads();

    if (tid < 64) {
        float s = 0.f, s2 = 0.f;
        #pragma unroll
        for (int c = 0; c < C_; c += 4) {
            const float4 v = *(const float4*)&xs[tid][c];
            s  += v.x + v.y + v.z + v.w;
            s2 += v.x*v.x + v.y*v.y + v.z*v.z + v.w*v.w;
        }
        const float mu  = s * (1.0f / 128.0f);
        const float var = s2 * (1.0f / 128.0f) - mu * mu;
        mu_s[tid] = mu;
        rs_s[tid] = rsqrtf(var + 0.001f);
    }
    __syncthreads();

    {
        const int tt = tid >> 2;
        const int c0 = (tid & 3) << 5;
        const float mu = mu_s[tt], rs = rs_s[tt];
        ushort_t* op = xln + (size_t)(tok0 + tt) * C_;
        #pragma unroll
        for (int j = 0; j < 8; ++j) {
            const int c = c0 + (j << 2);
            const float4 v  = *(const float4*)&xs[tt][c];
            const float4 gm = *(const float4*)(gamma + c);
            const float4 bt = *(const float4*)(beta + c);
            ushort4 o;
            o.x = f2b((v.x - mu) * rs * gm.x + bt.x);
            o.y = f2b((v.y - mu) * rs * gm.y + bt.y);
            o.z = f2b((v.z - mu) * rs * gm.z + bt.z);
            o.w = f2b((v.w - mu) * rs * gm.w + bt.w);
            *(ushort4*)(op + c) = o;
        }
    }
}

// ---------------------------------------------------------------------------
// K5: out = xln @ Wp + bp   (xln bf16 token-major, out fp32)
// ---------------------------------------------------------------------------
__global__ __launch_bounds__(256) void gemm_out(
    const ushort_t* __restrict__ xln, const float* __restrict__ Wp,
    const float* __restrict__ bp, float* __restrict__ out)
{
    __shared__ float smem[12288];
    float (*As)[64]  = (float(*)[64])smem;
    float (*Bs)[128] = (float(*)[128])(smem + 4096);

    const int tid  = threadIdx.x;
    const int tok0 = blockIdx.x * 64;
    const int t    = tid & 63;
    const int k4   = (tid >> 6) << 2;
    const int tx   = tid & 15, ty = tid >> 4;

    float acc[32] = {};
    for (int kc = 0; kc < C_; kc += 64) {
        __syncthreads();
        {
            const ushort_t* ap = xln + (size_t)(tok0 + t) * C_ + kc;
            #pragma unroll
            for (int kk = k4; kk < 64; kk += 16) {
                const ushort4 u = *(const ushort4*)(ap + kk);
                As[kk+0][t] = b2f(u.x); As[kk+1][t] = b2f(u.y);
                As[kk+2][t] = b2f(u.z); As[kk+3][t] = b2f(u.w);
            }
        }
        {
            const int n4b = (tid & 31) << 2;
            const int kr  = tid >> 5;
            #pragma unroll
            for (int kk = kr; kk < 64; kk += 8)
                *(float4*)&Bs[kk][n4b] = *(const float4*)(Wp + (size_t)(kc + kk) * C_ + n4b);
        }
        __syncthreads();
        #pragma unroll 4
        for (int k = 0; k < 64; ++k) {
            const float4 a  = *(const float4*)&As[k][ty << 2];
            const float4 b0 = *(const float4*)&Bs[k][tx << 2];
            const float4 b1 = *(const float4*)&Bs[k][64 + (tx << 2)];
            const float av[4] = {a.x, a.y, a.z, a.w};
            const float bv[8] = {b0.x, b0.y, b0.z, b0.w, b1.x, b1.y, b1.z, b1.w};
            #pragma unroll
            for (int i = 0; i < 4; ++i)
                #pragma unroll
                for (int j = 0; j < 8; ++j)
                    acc[i*8+j] += av[i] * bv[j];
        }
    }

    const int n1 = tx << 2, n2 = 64 + (tx << 2);
    const float4 b1 = *(const float4*)(bp + n1);
    const float4 b2 = *(const float4*)(bp + n2);
    #pragma unroll
    for (int i = 0; i < 4; ++i) {
        const int token = tok0 + (ty << 2) + i;
        float4 r1, r2;
        r1.x = acc[i*8+0] + b1.x; r1.y = acc[i*8+1] + b1.y;
        r1.z = acc[i*8+2] + b1.z; r1.w = acc[i*8+3] + b1.w;
        r2.x = acc[i*8+4] + b2.x; r2.y = acc[i*8+5] + b2.y;
        r2.z = acc[i*8+6] + b2.z; r2.w = acc[i*8+7] + b2.w;
        *(float4*)(out + (size_t)token * C_ + n1) = r1;
        *(float4*)(out + (size_t)token * C_ + n2) = r2;
    }
}

// ---------------------------------------------------------------------------
extern "C" void kernel_launch(void* const* d_in, const int* in_sizes, int n_in,
                              void* d_out, int out_size, void* d_ws, size_t ws_size,
                              hipStream_t stream) {
    const float* x     = (const float*)d_in[0];
    const float* Wf    = (const float*)d_in[1];
    const float* bf    = (const float*)d_in[2];
    const float* Wh    = (const float*)d_in[3];
    const float* bh    = (const float*)d_in[4];
    const float* gamma = (const float*)d_in[5];
    const float* beta  = (const float*)d_in[6];
    const float* Wp    = (const float*)d_in[7];
    const float* bp    = (const float*)d_in[8];
    const float* k0    = (const float*)d_in[9];
    const float* k1    = (const float*)d_in[10];
    const float* k2    = (const float*)d_in[11];
    float* out = (float*)d_out;

    const size_t NC = (size_t)NTOK * C_;
    ushort_t* P0  = (ushort_t*)d_ws;          // ctx transposed (then reused as xln)
    ushort_t* ACC = P0 + NC;                  // ctx_all (token-major)
    float* gates  = (float*)(ACC + NC);
    float* csum   = gates + (size_t)NTOK * 4;
    float* cglob  = csum + (size_t)B_ * C_;
    // total ~78 MB

    gemm_ctx_gates<<<NTOK / 64, 256, 0, stream>>>(x, Wf, bf, P0, gates, csum);
    focal_conv_fused<<<dim3(C_/8, (H_/TH)*(W_/TW), B_), 256, 0, stream>>>(
        P0, k0, k1, k2, gates, ACC, csum);
    mean_fin<<<(B_ * C_ + 255) / 256, 256, 0, stream>>>(csum, cglob);
    modq_ln<<<NTOK / 64, 256, 0, stream>>>(ACC, cglob, gates, x, Wf, bf, Wh, bh, gamma, beta, P0);
    gemm_out<<<NTOK / 64, 256, 0, stream>>>(P0, Wp, bp, out);
}